// Round 1
// baseline (230.658 us; speedup 1.0000x reference)
//
#include <hip/hip_runtime.h>

// FourierFFTLayer: ifft(fft(x, axis=-1)).real on real float32 input ==
// identity (FFT round-trip error ~1e-2 absmax vs 1.08e-1 threshold).
//
// rocprof evidence (prev round): timed region includes harness poison fills
// (2 x ~80us fillBufferAligned @ 84% HBM peak) that we cannot touch; our copy
// is the remaining ~60us (~4.5 TB/s). Ideal: 268 MB @ 6.3 TB/s = ~43us.
//
// This version: batch-of-8 float4 per thread (8 outstanding
// global_load_dwordx4 before stores -> full MLP), 4096 blocks (exact fit:
// 4096*256*8 = 8388608 float4s), nontemporal load/store (pure streaming,
// no reuse to protect -- poison fills evict LLC every iteration anyway).

typedef float f32x4 __attribute__((ext_vector_type(4)));

__global__ __launch_bounds__(256) void identity_copy_nt8(
        const f32x4* __restrict__ in, f32x4* __restrict__ out, int n4) {
    const int nth = gridDim.x * blockDim.x;
    int i = blockIdx.x * blockDim.x + threadIdx.x;

    // Main path: 8 float4s per thread, loads batched ahead of stores.
    for (; i + 7 * nth < n4; i += 8 * nth) {
        f32x4 v0 = __builtin_nontemporal_load(in + i + 0 * nth);
        f32x4 v1 = __builtin_nontemporal_load(in + i + 1 * nth);
        f32x4 v2 = __builtin_nontemporal_load(in + i + 2 * nth);
        f32x4 v3 = __builtin_nontemporal_load(in + i + 3 * nth);
        f32x4 v4 = __builtin_nontemporal_load(in + i + 4 * nth);
        f32x4 v5 = __builtin_nontemporal_load(in + i + 5 * nth);
        f32x4 v6 = __builtin_nontemporal_load(in + i + 6 * nth);
        f32x4 v7 = __builtin_nontemporal_load(in + i + 7 * nth);
        __builtin_nontemporal_store(v0, out + i + 0 * nth);
        __builtin_nontemporal_store(v1, out + i + 1 * nth);
        __builtin_nontemporal_store(v2, out + i + 2 * nth);
        __builtin_nontemporal_store(v3, out + i + 3 * nth);
        __builtin_nontemporal_store(v4, out + i + 4 * nth);
        __builtin_nontemporal_store(v5, out + i + 5 * nth);
        __builtin_nontemporal_store(v6, out + i + 6 * nth);
        __builtin_nontemporal_store(v7, out + i + 7 * nth);
    }
    // Tail (empty for the exact-fit launch below, kept for safety).
    for (; i < n4; i += nth) {
        __builtin_nontemporal_store(__builtin_nontemporal_load(in + i), out + i);
    }
}

extern "C" void kernel_launch(void* const* d_in, const int* in_sizes, int n_in,
                              void* d_out, int out_size, void* d_ws, size_t ws_size,
                              hipStream_t stream) {
    (void)in_sizes; (void)n_in; (void)d_ws; (void)ws_size;
    const f32x4* x = (const f32x4*)d_in[0];
    f32x4* out = (f32x4*)d_out;
    int n4 = out_size / 4;  // 33554432 floats / 4 = 8388608 float4s

    const int block = 256;
    const int per_thread = 8;
    // Exact fit for n4 = 8388608: 8388608 / (256*8) = 4096 blocks.
    int grid = (n4 + block * per_thread - 1) / (block * per_thread);
    identity_copy_nt8<<<grid, block, 0, stream>>>(x, out, n4);
}